// Round 1
// baseline (278.382 us; speedup 1.0000x reference)
//
#include <hip/hip_runtime.h>
#include <hip/hip_bf16.h>
#include <float.h>

#define BB 8
#define TT 20
#define NN 512
#define DD 64
#define BT (BB*TT)

// ---------------- K1: masked mean over nodes -> h_mean[bt][d] ----------------
__global__ __launch_bounds__(256) void kmean(const float* __restrict__ h,
                                             const int* __restrict__ mask,
                                             float* __restrict__ hmean) {
    int bt = blockIdx.x;
    int tid = threadIdx.x;
    int d = tid & 63, nc = tid >> 6;          // 4 chunks of 128 nodes
    const float* hp = h + (size_t)bt * NN * DD;
    const int* mp = mask + (size_t)bt * NN;
    float s = 0.f; int cnt = 0;
    for (int n = nc * 128; n < nc * 128 + 128; ++n) {
        int m = mp[n];
        if (m) { s += hp[(size_t)n * DD + d]; cnt++; }
    }
    __shared__ float sred[4][64];
    __shared__ int scnt[4];
    sred[nc][d] = s;
    if (d == 0) scnt[nc] = cnt;
    __syncthreads();
    if (nc == 0) {
        float tot = sred[0][d] + sred[1][d] + sred[2][d] + sred[3][d];
        int c = scnt[0] + scnt[1] + scnt[2] + scnt[3];
        hmean[(size_t)bt * DD + d] = tot / fmaxf((float)c, 1.f);
    }
}

// ---------------- K2: beta[b][t][u] = softmax_u(h_mean h_mean^T) ----------------
__global__ __launch_bounds__(256) void kbeta(const float* __restrict__ hmean,
                                             float* __restrict__ beta) {
    int b = blockIdx.x;
    int tid = threadIdx.x;
    __shared__ float hm[TT][DD];
    __shared__ float mb[TT][TT];
    for (int idx = tid; idx < TT * DD; idx += 256)
        hm[idx / DD][idx % DD] = hmean[(size_t)b * TT * DD + idx];
    __syncthreads();
    for (int p = tid; p < TT * TT; p += 256) {
        int t = p / TT, u = p % TT;
        float s = 0.f;
        for (int d = 0; d < DD; ++d) s += hm[t][d] * hm[u][d];
        mb[t][u] = s;
    }
    __syncthreads();
    if (tid < TT) {
        float mx = -FLT_MAX;
        for (int u = 0; u < TT; ++u) mx = fmaxf(mx, mb[tid][u]);
        float e[TT]; float sum = 0.f;
        for (int u = 0; u < TT; ++u) { e[u] = __expf(mb[tid][u] - mx); sum += e[u]; }
        float inv = 1.f / sum;
        for (int u = 0; u < TT; ++u)
            beta[((size_t)b * TT + tid) * TT + u] = e[u] * inv;
    }
}

// ---------------- K3: out = h + h_temporal  (staged into d_out) ----------------
// grid: B*32 blocks, 256 thr; each thread handles one float4 position q of N*D/4=8192.
__global__ __launch_bounds__(256) void ktemporal(const float* __restrict__ h,
                                                 const float* __restrict__ beta,
                                                 float* __restrict__ out) {
    int b = blockIdx.x >> 5;
    int q = (blockIdx.x & 31) * 256 + threadIdx.x;   // 0..8191
    __shared__ float cf[TT][TT];
    for (int idx = threadIdx.x; idx < TT * TT; idx += 256) {
        int t = idx / TT, u = idx % TT;
        cf[t][u] = beta[((size_t)b * TT + t) * TT + u] + (t == u ? 1.f : 0.f);
    }
    __syncthreads();
    const float4* hp = (const float4*)h + (size_t)b * TT * 8192;
    float4* op = (float4*)out + (size_t)b * TT * 8192;
    float4 hv[TT];
#pragma unroll
    for (int u = 0; u < TT; ++u) hv[u] = hp[(size_t)u * 8192 + q];
#pragma unroll
    for (int t = 0; t < TT; ++t) {
        float4 a = {0.f, 0.f, 0.f, 0.f};
#pragma unroll
        for (int u = 0; u < TT; ++u) {
            float c = cf[t][u];
            a.x += c * hv[u].x; a.y += c * hv[u].y;
            a.z += c * hv[u].z; a.w += c * hv[u].w;
        }
        op[(size_t)t * 8192 + q] = a;
    }
}

// ---------------- K4: spatial attention + final output ----------------
// grid: BT*8 blocks (64 rows each), 256 thr = 4 waves; wave owns 16 rows.
// Flash-style over 4 chunks of 128 j. out(d_out) already holds h+h_temporal.
__global__ __launch_bounds__(256) void kspatial(const float* __restrict__ h,
                                                const float* __restrict__ vel,
                                                const float* __restrict__ adj,
                                                const int* __restrict__ mask,
                                                float* __restrict__ out) {
    int blk = blockIdx.x;
    int bt = blk >> 3;
    int i0 = (blk & 7) * 64;
    int tid = threadIdx.x;
    int w = tid >> 6, lane = tid & 63;

    __shared__ float hc[128][64];     // h chunk (stride 64 -> 2-way on read, free)
    __shared__ float pl[4][128];      // per-wave p row
    __shared__ float2 vc[128];
    __shared__ int mc[128];

    const float* hp = h + (size_t)bt * NN * DD;
    const float* adjp = adj + (size_t)bt * NN * NN;
    const float2* velp = (const float2*)vel + (size_t)bt * NN;
    const int* mp = mask + (size_t)bt * NN;

    float acc[16], mrow[16], lrow[16];
    int rowm[16]; float2 rowv[16];
#pragma unroll
    for (int r = 0; r < 16; ++r) {
        acc[r] = 0.f; mrow[r] = -FLT_MAX; lrow[r] = 0.f;
        int i = i0 + w * 16 + r;
        rowm[r] = mp[i];
        rowv[r] = velp[i];
    }

    for (int c = 0; c < 4; ++c) {
        __syncthreads();
        const float4* src = (const float4*)(hp + (size_t)(c * 128) * DD);
        float4* dst = (float4*)(&hc[0][0]);
#pragma unroll
        for (int k = 0; k < 8; ++k) dst[tid + k * 256] = src[tid + k * 256];
        if (tid < 128) { vc[tid] = velp[c * 128 + tid]; mc[tid] = mp[c * 128 + tid]; }
        __syncthreads();

        float2 v1 = vc[lane], v2 = vc[lane + 64];
        int m1 = mc[lane], m2 = mc[lane + 64];

#pragma unroll
        for (int r = 0; r < 16; ++r) {
            if (!rowm[r]) continue;          // uniform per wave
            int i = i0 + w * 16 + r;
            const float* arow = adjp + (size_t)i * NN + c * 128;
            float a1 = arow[lane], a2 = arow[lane + 64];
            float2 vi = rowv[r];
            float dx1 = vi.x - v1.x, dy1 = vi.y - v1.y;
            float dx2 = vi.x - v2.x, dy2 = vi.y - v2.y;
            float l1 = m1 ? (a1 - (dx1 * dx1 + dy1 * dy1)) : -FLT_MAX;
            float l2 = m2 ? (a2 - (dx2 * dx2 + dy2 * dy2)) : -FLT_MAX;
            float cm = fmaxf(l1, l2);
#pragma unroll
            for (int s = 1; s < 64; s <<= 1) cm = fmaxf(cm, __shfl_xor(cm, s, 64));
            float nm = fmaxf(mrow[r], cm);
            float p1 = m1 ? __expf(l1 - nm) : 0.f;
            float p2 = m2 ? __expf(l2 - nm) : 0.f;
            float scale = __expf(mrow[r] - nm);
            float ps = p1 + p2;
#pragma unroll
            for (int s = 1; s < 64; s <<= 1) ps += __shfl_xor(ps, s, 64);
            mrow[r] = nm;
            lrow[r] = lrow[r] * scale + ps;
            pl[w][lane] = p1; pl[w][lane + 64] = p2;
            float a = acc[r] * scale;
#pragma unroll
            for (int jj = 0; jj < 128; jj += 4) {
                float4 pv = *(const float4*)&pl[w][jj];   // broadcast read
                a += pv.x * hc[jj + 0][lane];
                a += pv.y * hc[jj + 1][lane];
                a += pv.z * hc[jj + 2][lane];
                a += pv.w * hc[jj + 3][lane];
            }
            acc[r] = a;
        }
    }

    float* op = out + (size_t)bt * NN * DD;
#pragma unroll
    for (int r = 0; r < 16; ++r) {
        int i = i0 + w * 16 + r;
        if (rowm[r]) {
            float inv = 1.0f / fmaxf(lrow[r], 1e-8f);
            float tmp = op[(size_t)i * DD + lane];       // h + h_temporal
            op[(size_t)i * DD + lane] = tmp + acc[r] * inv;
        } else {
            op[(size_t)i * DD + lane] = 0.f;
        }
    }
}

extern "C" void kernel_launch(void* const* d_in, const int* in_sizes, int n_in,
                              void* d_out, int out_size, void* d_ws, size_t ws_size,
                              hipStream_t stream) {
    const float* h   = (const float*)d_in[0];
    const float* vel = (const float*)d_in[1];
    const float* adj = (const float*)d_in[2];
    const int* mask  = (const int*)d_in[3];
    float* out = (float*)d_out;

    float* hmean = (float*)d_ws;                       // BT*DD floats
    float* beta  = hmean + (size_t)BT * DD;            // BB*TT*TT floats

    kmean<<<BT, 256, 0, stream>>>(h, mask, hmean);
    kbeta<<<BB, 256, 0, stream>>>(hmean, beta);
    ktemporal<<<BB * 32, 256, 0, stream>>>(h, beta, out);
    kspatial<<<BT * 8, 256, 0, stream>>>(h, vel, adj, mask, out);
}

// Round 2
// 112.481 us; speedup vs baseline: 2.4749x; 2.4749x over previous
//
#include <hip/hip_runtime.h>
#include <float.h>

#define BB 8
#define TT 20
#define NN 512
#define DD 64
#define BT (BB*TT)

typedef __bf16 bf16x8 __attribute__((ext_vector_type(8)));
typedef float f32x4 __attribute__((ext_vector_type(4)));

// ---------- K1: bf16 transpose ht[bt][d][n] + masked mean (fused) ----------
__global__ __launch_bounds__(256) void ktransmean(const float* __restrict__ h,
                                                  const int* __restrict__ mask,
                                                  __bf16* __restrict__ ht,
                                                  float* __restrict__ hmean) {
    int bt = blockIdx.x;
    int tid = threadIdx.x;
    const float* hp = h + (size_t)bt * NN * DD;
    const int* mp = mask + (size_t)bt * NN;
    short* htp = (short*)(ht + (size_t)bt * DD * NN);

    __shared__ __bf16 t[64][132];
    __shared__ float sred[16][64];
    __shared__ int scnt;
    if (tid == 0) scnt = 0;

    int d4 = (tid & 15) << 2;
    float s0 = 0.f, s1 = 0.f, s2 = 0.f, s3 = 0.f;
    int mycnt = 0;

    for (int nb = 0; nb < 4; ++nb) {
        __syncthreads();
        for (int it = 0; it < 8; ++it) {
            int idx = it * 256 + tid;
            int nl = idx >> 4;                // 0..127
            int n = nb * 128 + nl;
            float4 v = *(const float4*)(hp + (size_t)n * DD + d4);
            int m = mp[n];
            if (m) {
                s0 += v.x; s1 += v.y; s2 += v.z; s3 += v.w;
                if ((tid & 15) == 0) mycnt++;
            }
            t[d4 + 0][nl] = (__bf16)v.x;
            t[d4 + 1][nl] = (__bf16)v.y;
            t[d4 + 2][nl] = (__bf16)v.z;
            t[d4 + 3][nl] = (__bf16)v.w;
        }
        __syncthreads();
        for (int it = 0; it < 8; ++it) {
            int idx = it * 256 + tid;
            int d = idx >> 5;                 // 0..63
            int s = idx & 31;                 // 0..31
            short4 v4 = *(const short4*)&t[d][4 * s];
            *(short4*)(htp + (size_t)d * NN + nb * 128 + 4 * s) = v4;
        }
    }
    int g = tid >> 4;
    sred[g][d4 + 0] = s0; sred[g][d4 + 1] = s1;
    sred[g][d4 + 2] = s2; sred[g][d4 + 3] = s3;
    if (mycnt) atomicAdd(&scnt, mycnt);
    __syncthreads();
    if (tid < 64) {
        float tot = 0.f;
#pragma unroll
        for (int k = 0; k < 16; ++k) tot += sred[k][tid];
        hmean[(size_t)bt * DD + tid] = tot / fmaxf((float)scnt, 1.f);
    }
}

// ---------- K2: per-bt column info + compacted unmasked row list ----------
__global__ __launch_bounds__(256) void kprep(const float* __restrict__ vel,
                                             const int* __restrict__ mask,
                                             float4* __restrict__ colinfo,
                                             int* __restrict__ rows,
                                             int* __restrict__ cnt) {
    int bt = blockIdx.x;
    int tid = threadIdx.x;
    __shared__ int lc;
    if (tid == 0) lc = 0;
    __syncthreads();
    for (int j = tid; j < NN; j += 256) {
        float2 v = ((const float2*)vel)[(size_t)bt * NN + j];
        int m = mask[(size_t)bt * NN + j];
        float ct = m ? -(v.x * v.x + v.y * v.y) : -3e38f;
        colinfo[(size_t)bt * NN + j] = make_float4(v.x, v.y, ct, 0.f);
        if (m) {
            int s = atomicAdd(&lc, 1);
            rows[(size_t)bt * NN + s] = j;
        }
    }
    __syncthreads();
    if (tid == 0) cnt[bt] = lc;
}

// ---------- K3: beta[b][t][u] = softmax_u(h_mean h_mean^T) ----------
__global__ __launch_bounds__(256) void kbeta(const float* __restrict__ hmean,
                                             float* __restrict__ beta) {
    int b = blockIdx.x;
    int tid = threadIdx.x;
    __shared__ float hm[TT][DD];
    __shared__ float mb[TT][TT];
    for (int idx = tid; idx < TT * DD; idx += 256)
        hm[idx / DD][idx % DD] = hmean[(size_t)b * TT * DD + idx];
    __syncthreads();
    for (int p = tid; p < TT * TT; p += 256) {
        int t = p / TT, u = p % TT;
        float s = 0.f;
        for (int d = 0; d < DD; ++d) s += hm[t][d] * hm[u][d];
        mb[t][u] = s;
    }
    __syncthreads();
    if (tid < TT) {
        float mx = -FLT_MAX;
        for (int u = 0; u < TT; ++u) mx = fmaxf(mx, mb[tid][u]);
        float e[TT]; float sum = 0.f;
        for (int u = 0; u < TT; ++u) { e[u] = __expf(mb[tid][u] - mx); sum += e[u]; }
        float inv = 1.f / sum;
        for (int u = 0; u < TT; ++u)
            beta[((size_t)b * TT + tid) * TT + u] = e[u] * inv;
    }
}

// ---------- K4: out = (h + h_temporal) * mask ----------
__global__ __launch_bounds__(256) void ktemporal(const float* __restrict__ h,
                                                 const float* __restrict__ beta,
                                                 const int* __restrict__ mask,
                                                 float* __restrict__ out) {
    int b = blockIdx.x >> 5;
    int q = (blockIdx.x & 31) * 256 + threadIdx.x;   // 0..8191 (n*16 + d4)
    int n = q >> 4;
    __shared__ float cf[TT][TT];
    for (int idx = threadIdx.x; idx < TT * TT; idx += 256) {
        int t = idx / TT, u = idx % TT;
        cf[t][u] = beta[((size_t)b * TT + t) * TT + u] + (t == u ? 1.f : 0.f);
    }
    __syncthreads();
    const float4* hp = (const float4*)h + (size_t)b * TT * 8192;
    float4* op = (float4*)out + (size_t)b * TT * 8192;
    const int* mp = mask + (size_t)b * TT * NN;
    float4 hv[TT];
#pragma unroll
    for (int u = 0; u < TT; ++u) hv[u] = hp[(size_t)u * 8192 + q];
    float4 z = {0.f, 0.f, 0.f, 0.f};
#pragma unroll
    for (int t = 0; t < TT; ++t) {
        float4 a = z;
#pragma unroll
        for (int u = 0; u < TT; ++u) {
            float c = cf[t][u];
            a.x += c * hv[u].x; a.y += c * hv[u].y;
            a.z += c * hv[u].z; a.w += c * hv[u].w;
        }
        int m = mp[(size_t)t * NN + n];
        op[(size_t)t * 8192 + q] = m ? a : z;
    }
}

// ---------- K5: spatial attention via MFMA, compacted rows ----------
// grid: BT*8 blocks; block = 4 waves; wave owns 16 compacted rows.
// Fixed softmax offset: logits < 1 always, so p = exp(logit - 1), no max pass.
__global__ __launch_bounds__(256) void kspatial(const float* __restrict__ adj,
                                                const float* __restrict__ vel,
                                                const int* __restrict__ cnt,
                                                const int* __restrict__ rows,
                                                const float4* __restrict__ colinfo,
                                                const __bf16* __restrict__ ht,
                                                float* __restrict__ out) {
    int bt = blockIdx.x >> 3;
    int i0 = (blockIdx.x & 7) * 64;
    int n_act = cnt[bt];
    if (i0 >= n_act) return;

    int tid = threadIdx.x;
    int w = tid >> 6, lane = tid & 63;
    int arow = lane & 15;      // A-fragment / C-column index
    int kg = lane >> 4;        // k-group (0..3)

    __shared__ float4 ci[NN];
    for (int idx = tid; idx < NN; idx += 256)
        ci[idx] = colinfo[(size_t)bt * NN + idx];

    int slot = i0 + w * 16 + arow;
    int slotc = slot < n_act ? slot : n_act - 1;
    int row = rows[(size_t)bt * NN + slotc];
    float2 rv = ((const float2*)vel)[(size_t)bt * NN + row];
    float ri = -(rv.x * rv.x + rv.y * rv.y) - 1.0f;   // -|vi|^2 - softmax offset
    float vx2 = 2.f * rv.x, vy2 = 2.f * rv.y;

    const float* arowp = adj + ((size_t)bt * NN + row) * NN;
    const __bf16* htb = ht + (size_t)bt * DD * NN;

    f32x4 zero = {0.f, 0.f, 0.f, 0.f};
    f32x4 acc[4];
#pragma unroll
    for (int nt = 0; nt < 4; ++nt) acc[nt] = zero;
    float lsum = 0.f;
    __syncthreads();

    for (int c = 0; c < 16; ++c) {
        int jb = c * 32 + kg * 8;
        float4 a01 = *(const float4*)(arowp + jb);
        float4 a23 = *(const float4*)(arowp + jb + 4);
        float p[8];
#pragma unroll
        for (int e = 0; e < 8; ++e) {
            float av = (e < 4) ? (&a01.x)[e] : (&a23.x)[e - 4];
            float4 cc = ci[jb + e];
            float l = av + cc.z + ri + vx2 * cc.x + vy2 * cc.y;
            p[e] = __expf(l);
        }
        lsum += ((p[0] + p[1]) + (p[2] + p[3])) + ((p[4] + p[5]) + (p[6] + p[7]));
        bf16x8 af;
#pragma unroll
        for (int e = 0; e < 8; ++e) af[e] = (__bf16)p[e];
#pragma unroll
        for (int nt = 0; nt < 4; ++nt) {
            bf16x8 bf = *(const bf16x8*)(htb + (size_t)(nt * 16 + arow) * NN + jb);
            acc[nt] = __builtin_amdgcn_mfma_f32_16x16x32_bf16(af, bf, acc[nt], 0, 0, 0);
        }
    }

    lsum += __shfl_xor(lsum, 16, 64);
    lsum += __shfl_xor(lsum, 32, 64);
    float inv = 1.0f / fmaxf(lsum, 1e-8f);

    float* op = out + (size_t)bt * NN * DD;
#pragma unroll
    for (int q = 0; q < 4; ++q) {
        int cr = kg * 4 + q;                 // C row within wave tile
        int s2 = i0 + w * 16 + cr;
        int r2 = __shfl(row, cr, 64);
        float iv = __shfl(inv, cr, 64);
        if (s2 < n_act) {
#pragma unroll
            for (int nt = 0; nt < 4; ++nt) {
                size_t o = (size_t)r2 * DD + nt * 16 + arow;
                op[o] = op[o] + acc[nt][q] * iv;
            }
        }
    }
}

extern "C" void kernel_launch(void* const* d_in, const int* in_sizes, int n_in,
                              void* d_out, int out_size, void* d_ws, size_t ws_size,
                              hipStream_t stream) {
    const float* h   = (const float*)d_in[0];
    const float* vel = (const float*)d_in[1];
    const float* adj = (const float*)d_in[2];
    const int* mask  = (const int*)d_in[3];
    float* out = (float*)d_out;

    char* ws = (char*)d_ws;
    __bf16* ht      = (__bf16*)ws;                       ws += (size_t)BT * DD * NN * 2;  // 10.49 MB
    float4* colinfo = (float4*)ws;                       ws += (size_t)BT * NN * 16;      // 1.31 MB
    float* hmean    = (float*)ws;                        ws += (size_t)BT * DD * 4;
    float* beta     = (float*)ws;                        ws += (size_t)BB * TT * TT * 4;
    int* rows       = (int*)ws;                          ws += (size_t)BT * NN * 4;
    int* cnt        = (int*)ws;

    ktransmean<<<BT, 256, 0, stream>>>(h, mask, ht, hmean);
    kprep<<<BT, 256, 0, stream>>>(vel, mask, colinfo, rows, cnt);
    kbeta<<<BB, 256, 0, stream>>>(hmean, beta);
    ktemporal<<<BB * 32, 256, 0, stream>>>(h, beta, mask, out);
    kspatial<<<BT * 8, 256, 0, stream>>>(adj, vel, cnt, rows, colinfo, ht, out);
}

// Round 3
// 106.898 us; speedup vs baseline: 2.6042x; 1.0522x over previous
//
#include <hip/hip_runtime.h>
#include <float.h>

#define BB 8
#define TT 20
#define NN 512
#define DD 64
#define BT (BB*TT)

typedef __bf16 bf16x8 __attribute__((ext_vector_type(8)));
typedef float f32x4 __attribute__((ext_vector_type(4)));

// ---------- K1: bf16 transpose ht[bt][d][n] + masked mean + colinfo + row compaction ----------
__global__ __launch_bounds__(256) void kpre(const float* __restrict__ h,
                                            const float* __restrict__ vel,
                                            const int* __restrict__ mask,
                                            __bf16* __restrict__ ht,
                                            float* __restrict__ hmean,
                                            float4* __restrict__ colinfo,
                                            int* __restrict__ rows,
                                            int* __restrict__ cnt) {
    int bt = blockIdx.x;
    int tid = threadIdx.x;
    const float* hp = h + (size_t)bt * NN * DD;
    const int* mp = mask + (size_t)bt * NN;
    const float2* velp = (const float2*)vel + (size_t)bt * NN;
    short* htp = (short*)(ht + (size_t)bt * DD * NN);

    __shared__ __bf16 t[64][132];
    __shared__ float sred[16][64];
    __shared__ int scnt;
    __shared__ int lc;
    if (tid == 0) { scnt = 0; lc = 0; }

    int d4 = (tid & 15) << 2;
    float s0 = 0.f, s1 = 0.f, s2 = 0.f, s3 = 0.f;
    int mycnt = 0;

    for (int nb = 0; nb < 4; ++nb) {
        __syncthreads();
        for (int it = 0; it < 8; ++it) {
            int idx = it * 256 + tid;
            int nl = idx >> 4;                // 0..127
            int n = nb * 128 + nl;
            float4 v = *(const float4*)(hp + (size_t)n * DD + d4);
            int m = mp[n];
            if (m) {
                s0 += v.x; s1 += v.y; s2 += v.z; s3 += v.w;
                if ((tid & 15) == 0) mycnt++;
            }
            t[d4 + 0][nl] = (__bf16)v.x;
            t[d4 + 1][nl] = (__bf16)v.y;
            t[d4 + 2][nl] = (__bf16)v.z;
            t[d4 + 3][nl] = (__bf16)v.w;
        }
        __syncthreads();
        for (int it = 0; it < 8; ++it) {
            int idx = it * 256 + tid;
            int d = idx >> 5;                 // 0..63
            int s = idx & 31;                 // 0..31
            short4 v4 = *(const short4*)&t[d][4 * s];
            *(short4*)(htp + (size_t)d * NN + nb * 128 + 4 * s) = v4;
        }
    }
    int g = tid >> 4;
    sred[g][d4 + 0] = s0; sred[g][d4 + 1] = s1;
    sred[g][d4 + 2] = s2; sred[g][d4 + 3] = s3;
    if (mycnt) atomicAdd(&scnt, mycnt);
    __syncthreads();
    if (tid < 64) {
        float tot = 0.f;
#pragma unroll
        for (int k = 0; k < 16; ++k) tot += sred[k][tid];
        hmean[(size_t)bt * DD + tid] = tot / fmaxf((float)scnt, 1.f);
    }

    // colinfo + compacted active-row list (1 atomic per wave via ballot)
    int lane = tid & 63;
#pragma unroll
    for (int rpt = 0; rpt < 2; ++rpt) {
        int j = rpt * 256 + tid;
        float2 v = velp[j];
        int m = mp[j];
        float cz = m ? -(v.x * v.x + v.y * v.y) : -3e38f;
        colinfo[(size_t)bt * NN + j] = make_float4(v.x, v.y, cz, 0.f);
        unsigned long long bal = __ballot(m != 0);
        int pos = __popcll(bal & ((1ull << lane) - 1ull));
        int tot = __popcll(bal);
        int base = 0;
        if (lane == 0 && tot) base = atomicAdd(&lc, tot);
        base = __shfl(base, 0, 64);
        if (m) rows[(size_t)bt * NN + base + pos] = j;
    }
    __syncthreads();
    if (tid == 0) cnt[bt] = lc;
}

// ---------- K2: beta[b][t][u] = softmax_u(h_mean h_mean^T) ----------
__global__ __launch_bounds__(256) void kbeta(const float* __restrict__ hmean,
                                             float* __restrict__ beta) {
    int b = blockIdx.x;
    int tid = threadIdx.x;
    __shared__ float hm[TT][DD];
    __shared__ float mb[TT][TT];
    for (int idx = tid; idx < TT * DD; idx += 256)
        hm[idx / DD][idx % DD] = hmean[(size_t)b * TT * DD + idx];
    __syncthreads();
    for (int p = tid; p < TT * TT; p += 256) {
        int t = p / TT, u = p % TT;
        float s = 0.f;
        for (int d = 0; d < DD; ++d) s += hm[t][d] * hm[u][d];
        mb[t][u] = s;
    }
    __syncthreads();
    if (tid < TT) {
        float mx = -FLT_MAX;
        for (int u = 0; u < TT; ++u) mx = fmaxf(mx, mb[tid][u]);
        float e[TT]; float sum = 0.f;
        for (int u = 0; u < TT; ++u) { e[u] = __expf(mb[tid][u] - mx); sum += e[u]; }
        float inv = 1.f / sum;
        for (int u = 0; u < TT; ++u)
            beta[((size_t)b * TT + tid) * TT + u] = e[u] * inv;
    }
}

// ---------- K3: out = (h + h_temporal) * mask ---------- (float2 grain, 2x waves)
__global__ __launch_bounds__(256) void ktemporal(const float* __restrict__ h,
                                                 const float* __restrict__ beta,
                                                 const int* __restrict__ mask,
                                                 float* __restrict__ out) {
    int b = blockIdx.x >> 6;
    int q = (blockIdx.x & 63) * 256 + threadIdx.x;   // 0..16383 float2 slots
    int n = q >> 5;
    __shared__ float cf[TT][TT];
    for (int idx = threadIdx.x; idx < TT * TT; idx += 256) {
        int t = idx / TT, u = idx % TT;
        cf[t][u] = beta[((size_t)b * TT + t) * TT + u] + (t == u ? 1.f : 0.f);
    }
    __syncthreads();
    const float2* hp = (const float2*)h + (size_t)b * TT * 16384;
    float2* op = (float2*)out + (size_t)b * TT * 16384;
    const int* mp = mask + (size_t)b * TT * NN;
    float2 hv[TT];
#pragma unroll
    for (int u = 0; u < TT; ++u) hv[u] = hp[(size_t)u * 16384 + q];
    float2 z = {0.f, 0.f};
#pragma unroll
    for (int t = 0; t < TT; ++t) {
        float2 a = z;
#pragma unroll
        for (int u = 0; u < TT; ++u) {
            float c = cf[t][u];
            a.x += c * hv[u].x; a.y += c * hv[u].y;
        }
        int m = mp[(size_t)t * NN + n];
        op[(size_t)t * 16384 + q] = m ? a : z;
    }
}

// ---------- K4: spatial attention, MFMA, 8 waves (4 row-groups x 2 j-halves) ----------
// p = exp(adj_ij + 2 vi.vj - |vj|^2)  (per-row constants cancel in p/sum p)
__global__ __launch_bounds__(512) void kspatial(const float* __restrict__ adj,
                                                const float* __restrict__ vel,
                                                const int* __restrict__ cnt,
                                                const int* __restrict__ rows,
                                                const float4* __restrict__ colinfo,
                                                const __bf16* __restrict__ ht,
                                                float* __restrict__ out) {
    int bt = blockIdx.x >> 3;
    int i0 = (blockIdx.x & 7) * 64;
    int n_act = cnt[bt];
    if (i0 >= n_act) return;

    int tid = threadIdx.x;
    int w = tid >> 6, lane = tid & 63;
    int rg = w >> 1, jh = w & 1;       // row-group 0..3, j-half 0..1
    int arow = lane & 15;              // A row / C col index
    int kg = lane >> 4;                // k-group 0..3

    __shared__ float4 ci[NN];
    __shared__ float comb[4][64][17];

    for (int idx = tid; idx < NN; idx += 512)
        ci[idx] = colinfo[(size_t)bt * NN + idx];

    int slot = i0 + rg * 16 + arow;
    int slotc = slot < n_act ? slot : n_act - 1;
    int row = rows[(size_t)bt * NN + slotc];
    float2 rv = ((const float2*)vel)[(size_t)bt * NN + row];
    float vx2 = 2.f * rv.x, vy2 = 2.f * rv.y;

    const float* arowp = adj + ((size_t)bt * NN + row) * NN + jh * 256;
    const __bf16* htb = ht + (size_t)bt * DD * NN + jh * 256;

    f32x4 zero = {0.f, 0.f, 0.f, 0.f};
    f32x4 acc[4];
#pragma unroll
    for (int nt = 0; nt < 4; ++nt) acc[nt] = zero;
    float lsum = 0.f;
    __syncthreads();

    int jb = kg * 8;
    float4 a01 = *(const float4*)(arowp + jb);
    float4 a23 = *(const float4*)(arowp + jb + 4);
#pragma unroll
    for (int c = 0; c < 8; ++c) {
        float4 n01, n23;
        if (c < 7) {
            n01 = *(const float4*)(arowp + jb + 32);
            n23 = *(const float4*)(arowp + jb + 36);
        }
        const float4* ccp = &ci[jh * 256 + jb];
        float p[8];
#pragma unroll
        for (int e = 0; e < 8; ++e) {
            float av = (e < 4) ? (&a01.x)[e] : (&a23.x)[e - 4];
            float4 cc = ccp[e];
            float l = av + cc.z + vx2 * cc.x + vy2 * cc.y;
            p[e] = __expf(l);
        }
        lsum += ((p[0] + p[1]) + (p[2] + p[3])) + ((p[4] + p[5]) + (p[6] + p[7]));
        bf16x8 af;
#pragma unroll
        for (int e = 0; e < 8; ++e) af[e] = (__bf16)p[e];
#pragma unroll
        for (int nt = 0; nt < 4; ++nt) {
            bf16x8 bf = *(const bf16x8*)(htb + (size_t)(nt * 16 + arow) * NN + jb);
            acc[nt] = __builtin_amdgcn_mfma_f32_16x16x32_bf16(af, bf, acc[nt], 0, 0, 0);
        }
        jb += 32;
        a01 = n01; a23 = n23;
    }

    lsum += __shfl_xor(lsum, 16, 64);
    lsum += __shfl_xor(lsum, 32, 64);

    if (jh == 1) {
#pragma unroll
        for (int nt = 0; nt < 4; ++nt)
#pragma unroll
            for (int q = 0; q < 4; ++q)
                comb[rg][lane][nt * 4 + q] = acc[nt][q];
        comb[rg][lane][16] = lsum;
    }
    __syncthreads();
    if (jh == 0) {
#pragma unroll
        for (int nt = 0; nt < 4; ++nt)
#pragma unroll
            for (int q = 0; q < 4; ++q)
                acc[nt][q] += comb[rg][lane][nt * 4 + q];
        lsum += comb[rg][lane][16];
        float inv = 1.0f / fmaxf(lsum, 1e-8f);

        float* op = out + (size_t)bt * NN * DD;
#pragma unroll
        for (int q = 0; q < 4; ++q) {
            int cr = kg * 4 + q;                 // C row within wave tile
            int s2 = i0 + rg * 16 + cr;
            int r2 = __shfl(row, cr, 64);
            float iv = __shfl(inv, cr, 64);
            if (s2 < n_act) {
#pragma unroll
                for (int nt = 0; nt < 4; ++nt) {
                    size_t o = (size_t)r2 * DD + nt * 16 + arow;
                    op[o] = op[o] + acc[nt][q] * iv;
                }
            }
        }
    }
}

extern "C" void kernel_launch(void* const* d_in, const int* in_sizes, int n_in,
                              void* d_out, int out_size, void* d_ws, size_t ws_size,
                              hipStream_t stream) {
    const float* h   = (const float*)d_in[0];
    const float* vel = (const float*)d_in[1];
    const float* adj = (const float*)d_in[2];
    const int* mask  = (const int*)d_in[3];
    float* out = (float*)d_out;

    char* ws = (char*)d_ws;
    __bf16* ht      = (__bf16*)ws;                       ws += (size_t)BT * DD * NN * 2;
    float4* colinfo = (float4*)ws;                       ws += (size_t)BT * NN * 16;
    float* hmean    = (float*)ws;                        ws += (size_t)BT * DD * 4;
    float* beta     = (float*)ws;                        ws += (size_t)BB * TT * TT * 4;
    int* rows       = (int*)ws;                          ws += (size_t)BT * NN * 4;
    int* cnt        = (int*)ws;

    kpre<<<BT, 256, 0, stream>>>(h, vel, mask, ht, hmean, colinfo, rows, cnt);
    kbeta<<<BB, 256, 0, stream>>>(hmean, beta);
    ktemporal<<<BB * 64, 256, 0, stream>>>(h, beta, mask, out);
    kspatial<<<BT * 8, 512, 0, stream>>>(adj, vel, cnt, rows, colinfo, ht, out);
}

// Round 5
// 97.277 us; speedup vs baseline: 2.8618x; 1.0989x over previous
//
#include <hip/hip_runtime.h>
#include <float.h>

#define BB 8
#define TT 20
#define NN 512
#define DD 64
#define BT (BB*TT)

typedef __bf16 bf16x8 __attribute__((ext_vector_type(8)));
typedef float f32x4 __attribute__((ext_vector_type(4)));

// ---------- K1: per-slice (64 nodes) transpose + partial mean + colinfo + compaction ----------
// grid BT*8 blocks, 256 thr.
__global__ __launch_bounds__(256) void kpre(const float* __restrict__ h,
                                            const float* __restrict__ vel,
                                            const int* __restrict__ mask,
                                            __bf16* __restrict__ ht,
                                            float* __restrict__ hpart,
                                            int* __restrict__ cpart,
                                            float4* __restrict__ colinfo,
                                            int* __restrict__ rows,
                                            int* __restrict__ cnt) {
    int bx = blockIdx.x;
    int bt = bx >> 3, slice = bx & 7;
    int n0 = slice * 64;
    int tid = threadIdx.x;
    const float* hp = h + ((size_t)bt * NN + n0) * DD;
    const int* mp = mask + (size_t)bt * NN + n0;
    short* htp = (short*)(ht + (size_t)bt * DD * NN) + n0;

    __shared__ __bf16 t[64][72];
    __shared__ float sred[16][64];

    int d4 = (tid & 15) << 2;
    int nl0 = tid >> 4;
    float s0 = 0.f, s1 = 0.f, s2 = 0.f, s3 = 0.f;
#pragma unroll
    for (int it = 0; it < 4; ++it) {
        int nl = it * 16 + nl0;
        float4 v = *(const float4*)(hp + (size_t)nl * DD + d4);
        if (mp[nl]) { s0 += v.x; s1 += v.y; s2 += v.z; s3 += v.w; }
        t[d4 + 0][nl] = (__bf16)v.x;
        t[d4 + 1][nl] = (__bf16)v.y;
        t[d4 + 2][nl] = (__bf16)v.z;
        t[d4 + 3][nl] = (__bf16)v.w;
    }
    int g = tid >> 4;
    sred[g][d4 + 0] = s0; sred[g][d4 + 1] = s1;
    sred[g][d4 + 2] = s2; sred[g][d4 + 3] = s3;
    __syncthreads();
#pragma unroll
    for (int it = 0; it < 4; ++it) {
        int idx = it * 256 + tid;
        int d = idx >> 4, s = idx & 15;
        short4 v4 = *(const short4*)&t[d][4 * s];
        *(short4*)(htp + (size_t)d * NN + 4 * s) = v4;
    }
    if (tid < 64) {
        float tot = 0.f;
#pragma unroll
        for (int k = 0; k < 16; ++k) tot += sred[k][tid];
        hpart[(size_t)bx * DD + tid] = tot;
    }
    if (tid < 64) {                       // wave 0: colinfo + compaction
        int j = n0 + tid;
        float2 v = ((const float2*)vel)[(size_t)bt * NN + j];
        int m = mp[tid];
        float cz = m ? -(v.x * v.x + v.y * v.y) : -3e38f;
        colinfo[(size_t)bt * NN + j] = make_float4(v.x, v.y, cz, 0.f);
        unsigned long long bal = __ballot(m != 0);
        int pos = __popcll(bal & ((1ull << tid) - 1ull));
        int totc = __popcll(bal);
        int base = 0;
        if (tid == 0) { base = atomicAdd(&cnt[bt], totc); cpart[bx] = totc; }
        base = __shfl(base, 0, 64);
        if (m) rows[(size_t)bt * NN + base + pos] = j;
    }
}

// ---------- K2: finalize hmean from partials, then beta = softmax(hmean hmean^T) ----------
__global__ __launch_bounds__(256) void kbeta(const float* __restrict__ hpart,
                                             const int* __restrict__ cpart,
                                             float* __restrict__ beta) {
    int b = blockIdx.x;
    int tid = threadIdx.x;
    __shared__ float hm[TT][DD];
    __shared__ float mb[TT][TT];
    __shared__ float invc[TT];
    if (tid < TT) {
        int c = 0;
#pragma unroll
        for (int k = 0; k < 8; ++k) c += cpart[(b * TT + tid) * 8 + k];
        invc[tid] = 1.f / fmaxf((float)c, 1.f);
    }
    __syncthreads();
    for (int idx = tid; idx < TT * DD; idx += 256) {
        int t = idx / DD, d = idx % DD;
        const float* pp = hpart + ((size_t)(b * TT + t) * 8) * DD + d;
        float s = 0.f;
#pragma unroll
        for (int k = 0; k < 8; ++k) s += pp[k * DD];
        hm[t][d] = s * invc[t];
    }
    __syncthreads();
    for (int p = tid; p < TT * TT; p += 256) {
        int t = p / TT, u = p % TT;
        float s = 0.f;
        for (int d = 0; d < DD; ++d) s += hm[t][d] * hm[u][d];
        mb[t][u] = s;
    }
    __syncthreads();
    if (tid < TT) {
        float mx = -FLT_MAX;
        for (int u = 0; u < TT; ++u) mx = fmaxf(mx, mb[tid][u]);
        float e[TT]; float sum = 0.f;
        for (int u = 0; u < TT; ++u) { e[u] = __expf(mb[tid][u] - mx); sum += e[u]; }
        float inv = 1.f / sum;
        for (int u = 0; u < TT; ++u)
            beta[((size_t)b * TT + tid) * TT + u] = e[u] * inv;
    }
}

// ---------- K3: out = (h + h_temporal) * mask ----------
__global__ __launch_bounds__(256) void ktemporal(const float* __restrict__ h,
                                                 const float* __restrict__ beta,
                                                 const int* __restrict__ mask,
                                                 float* __restrict__ out) {
    int b = blockIdx.x >> 6;
    int q = (blockIdx.x & 63) * 256 + threadIdx.x;   // 0..16383 float2 slots
    int n = q >> 5;
    __shared__ float cf[TT][TT];
    for (int idx = threadIdx.x; idx < TT * TT; idx += 256) {
        int t = idx / TT, u = idx % TT;
        cf[t][u] = beta[((size_t)b * TT + t) * TT + u] + (t == u ? 1.f : 0.f);
    }
    __syncthreads();
    const float2* hp = (const float2*)h + (size_t)b * TT * 16384;
    float2* op = (float2*)out + (size_t)b * TT * 16384;
    const int* mp = mask + (size_t)b * TT * NN;
    float2 hv[TT];
#pragma unroll
    for (int u = 0; u < TT; ++u) hv[u] = hp[(size_t)u * 16384 + q];
    float2 z = {0.f, 0.f};
#pragma unroll
    for (int t = 0; t < TT; ++t) {
        float2 a = z;
#pragma unroll
        for (int u = 0; u < TT; ++u) {
            float c = cf[t][u];
            a.x += c * hv[u].x; a.y += c * hv[u].y;
        }
        int m = mp[(size_t)t * NN + n];
        op[(size_t)t * 16384 + q] = m ? a : z;
    }
}

// ---------- K4: spatial attention, MFMA, XCD-affine blocks ----------
// p = exp(adj_ij + 2 vi.vj - |vj|^2); per-row constants cancel in softmax.
__global__ __launch_bounds__(512) void kspatial(const float* __restrict__ adj,
                                                const float* __restrict__ vel,
                                                const int* __restrict__ cnt,
                                                const int* __restrict__ rows,
                                                const float4* __restrict__ colinfo,
                                                const __bf16* __restrict__ ht,
                                                float* __restrict__ out) {
    // XCD-affinity swizzle: all 8 row-blocks of one bt land on the same XCD
    // (dispatch round-robins blockIdx%8 across the 8 XCDs; 1280%8==0 -> bijective)
    int bx = blockIdx.x;
    int x = bx & 7;
    int m8 = bx >> 3;                  // 0..159
    int bt = x * 20 + (m8 >> 3);
    int i0 = (m8 & 7) * 64;
    int n_act = cnt[bt];
    if (i0 >= n_act) return;

    int tid = threadIdx.x;
    int w = tid >> 6, lane = tid & 63;
    int rg = w >> 1, jh = w & 1;       // row-group 0..3, j-half 0..1
    int arow = lane & 15;              // A row / C col index
    int kg = lane >> 4;                // k-group 0..3

    __shared__ float4 ci[NN];
    __shared__ float comb[4][64][17];

    for (int idx = tid; idx < NN; idx += 512)
        ci[idx] = colinfo[(size_t)bt * NN + idx];

    int slot = i0 + rg * 16 + arow;
    int slotc = slot < n_act ? slot : n_act - 1;
    int row = rows[(size_t)bt * NN + slotc];
    float2 rv = ((const float2*)vel)[(size_t)bt * NN + row];
    float vx2 = 2.f * rv.x, vy2 = 2.f * rv.y;

    const float* arowp = adj + ((size_t)bt * NN + row) * NN + jh * 256;
    const __bf16* htb = ht + (size_t)bt * DD * NN + jh * 256;

    f32x4 zero = {0.f, 0.f, 0.f, 0.f};
    f32x4 acc[4];
#pragma unroll
    for (int nt = 0; nt < 4; ++nt) acc[nt] = zero;
    float lsum = 0.f;
    __syncthreads();

    int jb = kg * 8;
    f32x4 a01 = __builtin_nontemporal_load((const f32x4*)(arowp + jb));
    f32x4 a23 = __builtin_nontemporal_load((const f32x4*)(arowp + jb + 4));
#pragma unroll
    for (int c = 0; c < 8; ++c) {
        f32x4 n01, n23;
        if (c < 7) {
            n01 = __builtin_nontemporal_load((const f32x4*)(arowp + jb + 32));
            n23 = __builtin_nontemporal_load((const f32x4*)(arowp + jb + 36));
        }
        const float4* ccp = &ci[jh * 256 + jb];
        float p[8];
#pragma unroll
        for (int e = 0; e < 8; ++e) {
            float av = (e < 4) ? a01[e] : a23[e - 4];
            float4 cc = ccp[e];
            float l = av + cc.z + vx2 * cc.x + vy2 * cc.y;
            p[e] = __expf(l);
        }
        lsum += ((p[0] + p[1]) + (p[2] + p[3])) + ((p[4] + p[5]) + (p[6] + p[7]));
        bf16x8 af;
#pragma unroll
        for (int e = 0; e < 8; ++e) af[e] = (__bf16)p[e];
#pragma unroll
        for (int nt = 0; nt < 4; ++nt) {
            bf16x8 bf = *(const bf16x8*)(htb + (size_t)(nt * 16 + arow) * NN + jb);
            acc[nt] = __builtin_amdgcn_mfma_f32_16x16x32_bf16(af, bf, acc[nt], 0, 0, 0);
        }
        jb += 32;
        a01 = n01; a23 = n23;
    }

    lsum += __shfl_xor(lsum, 16, 64);
    lsum += __shfl_xor(lsum, 32, 64);

    if (jh == 1) {
#pragma unroll
        for (int nt = 0; nt < 4; ++nt)
#pragma unroll
            for (int q = 0; q < 4; ++q)
                comb[rg][lane][nt * 4 + q] = acc[nt][q];
        comb[rg][lane][16] = lsum;
    }
    __syncthreads();
    if (jh == 0) {
#pragma unroll
        for (int nt = 0; nt < 4; ++nt)
#pragma unroll
            for (int q = 0; q < 4; ++q)
                acc[nt][q] += comb[rg][lane][nt * 4 + q];
        lsum += comb[rg][lane][16];
        float inv = 1.0f / fmaxf(lsum, 1e-8f);

        float* op = out + (size_t)bt * NN * DD;
#pragma unroll
        for (int q = 0; q < 4; ++q) {
            int cr = kg * 4 + q;
            int s2 = i0 + rg * 16 + cr;
            int r2 = __shfl(row, cr, 64);
            float iv = __shfl(inv, cr, 64);
            if (s2 < n_act) {
#pragma unroll
                for (int nt = 0; nt < 4; ++nt) {
                    size_t o = (size_t)r2 * DD + nt * 16 + arow;
                    op[o] = op[o] + acc[nt][q] * iv;
                }
            }
        }
    }
}

extern "C" void kernel_launch(void* const* d_in, const int* in_sizes, int n_in,
                              void* d_out, int out_size, void* d_ws, size_t ws_size,
                              hipStream_t stream) {
    const float* h   = (const float*)d_in[0];
    const float* vel = (const float*)d_in[1];
    const float* adj = (const float*)d_in[2];
    const int* mask  = (const int*)d_in[3];
    float* out = (float*)d_out;

    char* ws = (char*)d_ws;
    __bf16* ht      = (__bf16*)ws;                       ws += (size_t)BT * DD * NN * 2;
    float4* colinfo = (float4*)ws;                       ws += (size_t)BT * NN * 16;
    float* hpart    = (float*)ws;                        ws += (size_t)BT * 8 * DD * 4;
    int* cpart      = (int*)ws;                          ws += (size_t)BT * 8 * 4;
    float* beta     = (float*)ws;                        ws += (size_t)BB * TT * TT * 4;
    int* rows       = (int*)ws;                          ws += (size_t)BT * NN * 4;
    int* cnt        = (int*)ws;

    (void)hipMemsetAsync(cnt, 0, BT * sizeof(int), stream);
    kpre<<<BT * 8, 256, 0, stream>>>(h, vel, mask, ht, hpart, cpart, colinfo, rows, cnt);
    kbeta<<<BB, 256, 0, stream>>>(hpart, cpart, beta);
    ktemporal<<<BB * 64, 256, 0, stream>>>(h, beta, mask, out);
    kspatial<<<BT * 8, 512, 0, stream>>>(adj, vel, cnt, rows, colinfo, ht, out);
}